// Round 5
// baseline (143.440 us; speedup 1.0000x reference)
//
#include <hip/hip_runtime.h>
#include <hip/hip_bf16.h>
#include <math.h>

typedef _Float16 half8 __attribute__((ext_vector_type(8)));
typedef float f32x4 __attribute__((ext_vector_type(4)));

#define BATCH 100
#define CH    512
#define HWP   256
#define SAMP  (CH * HWP)   // 131072 elems per sample

// ---- async global->LDS 16B (wave-uniform LDS base + lane*16) ----
__device__ __forceinline__ void async16(const void* g, void* l) {
  __builtin_amdgcn_global_load_lds(
      (const __attribute__((address_space(1))) unsigned int*)g,
      (__attribute__((address_space(3))) unsigned int*)l, 16, 0, 0);
}

// ---- K0: transpose + fp32->fp16 (blocks <3200)  |  W fp32->fp16 (blocks >=3200)
__global__ __launch_bounds__(256) void k_txpose(const float* __restrict__ x,
                                               _Float16* __restrict__ xh,
                                               const float* __restrict__ W,
                                               _Float16* __restrict__ Wh) {
  int bid = blockIdx.x;
  int t = threadIdx.x;
  if (bid >= 3200) {            // W conversion: 256 blocks x 1024 elems
    int base = (bid - 3200) * 1024 + t;
#pragma unroll
    for (int j = 0; j < 4; j++) Wh[base + j * 256] = (_Float16)W[base + j * 256];
    return;
  }
  __shared__ float tb[64][69];  // pad 5 -> 2-way max bank alias (free)
  int b    = bid >> 5;          // 32 tiles per batch
  int tile = bid & 31;
  int c0 = (tile >> 2) << 6;    // 8 c-tiles of 64
  int p0 = (tile & 3) << 6;     // 4 p-tiles of 64
  const float* xb = x + (size_t)b * SAMP;
#pragma unroll
  for (int it = 0; it < 4; it++) {
    int ch = it * 256 + t;
    int c  = ch >> 4;           // 0..63
    int pc = (ch & 15) << 2;    // 0..60
    float4 v = *(const float4*)(xb + (size_t)(c0 + c) * HWP + p0 + pc);
    tb[c][pc] = v.x; tb[c][pc + 1] = v.y; tb[c][pc + 2] = v.z; tb[c][pc + 3] = v.w;
  }
  __syncthreads();
  _Float16* xhb = xh + (size_t)b * SAMP;
#pragma unroll
  for (int it = 0; it < 2; it++) {
    int ch = it * 256 + t;
    int p  = ch >> 3;           // 0..63
    int ck = (ch & 7) << 3;     // 0..56
    half8 h;
#pragma unroll
    for (int j = 0; j < 8; j++) h[j] = (_Float16)tb[ck + j][p];
    *(half8*)(xhb + (size_t)(p0 + p) * CH + c0 + ck) = h;
  }
}

// ---- K1: batched GEMM + fused exp + denom partial + u = x*e (fp16).
// logit[b][o][p] = sum_c W[o][c]*x[b][c][p] + bias[o];  u = x[b][o][p]*exp(logit)
// A = Wh (o,c); B^T = xh[b] (p,c). 128x128 tile, BK=32.
// x sub-tile for the epilogue is captured from L2-hot lines during the
// matching K-iterations (kk in [o0,o0+128)) -> no epilogue HBM re-fetch.
// u-tile goes through LDS for coalesced half8 stores.
__global__ __launch_bounds__(256) void k_gemm(const _Float16* __restrict__ Wh,
                                             const _Float16* __restrict__ xh,
                                             const float* __restrict__ bias,
                                             _Float16* __restrict__ u,
                                             float* __restrict__ denom) {
  __shared__ __align__(16) _Float16 As[128 * 32];     //  8 KB
  __shared__ __align__(16) _Float16 Bs[128 * 32];     //  8 KB
  __shared__ __align__(16) _Float16 xk[128 * 136];    // 34.8 KB: x-tile [p][o] pad8; reused as u-tile [o][p] pad8
  __shared__ float rs[4];
  int bid   = blockIdx.x;
  int batch = bid >> 3;
  int sub   = bid & 7;
  int ot = sub & 3, pt = sub >> 2;     // o-tile fastest: 4 o-tiles share one x-tile in L2
  int o0 = ot * 128, p0 = pt * 128;
  const _Float16* Bg = xh + (size_t)batch * SAMP;   // [p][c] 256x512

  int t  = threadIdx.x;
  int wv = t >> 6, ln = t & 63;
  int qd = ln >> 4, r = ln & 15;
  int wm0 = (wv >> 1) * 64, wn0 = (wv & 1) * 64;

  f32x4 acc[4][4] = {};

  for (int kk = 0; kk < 512; kk += 32) {
#pragma unroll
    for (int it = 0; it < 2; it++) {
      int ch  = it * 256 + t;         // 0..511 chunks of 16B
      int row = ch >> 2;              // 0..127
      int qc  = ch & 3;               // 4 chunks per 64B row
      char* la = (char*)As + (size_t)(it * 256 + wv * 64) * 16;   // wave-uniform
      char* lb = (char*)Bs + (size_t)(it * 256 + wv * 64) * 16;
      async16((const char*)(Wh + (size_t)(o0 + row) * 512 + kk + qc * 8), la);
      async16((const char*)(Bg + (size_t)(p0 + row) * 512 + kk + qc * 8), lb);
    }
    // capture x sub-tile while its lines are L2/L1-hot (independent of Bs)
    if ((unsigned)(kk - o0) < 128u) {
      int ko = kk - o0;
#pragma unroll
      for (int it = 0; it < 2; it++) {
        int ch  = it * 256 + t;
        int row = ch >> 2;
        int qc  = ch & 3;
        half8 v = *(const half8*)(Bg + (size_t)(p0 + row) * 512 + kk + qc * 8);
        *(half8*)(xk + row * 136 + ko + qc * 8) = v;
      }
    }
    __syncthreads();
    half8 af[4], bf[4];
#pragma unroll
    for (int i = 0; i < 4; i++)
      af[i] = *(const half8*)(As + (wm0 + i * 16 + r) * 32 + qd * 8);
#pragma unroll
    for (int j = 0; j < 4; j++)
      bf[j] = *(const half8*)(Bs + (wn0 + j * 16 + r) * 32 + qd * 8);
#pragma unroll
    for (int i = 0; i < 4; i++)
#pragma unroll
      for (int j = 0; j < 4; j++)
        acc[i][j] = __builtin_amdgcn_mfma_f32_16x16x32_f16(af[i], bf[j], acc[i][j], 0, 0, 0);
    __syncthreads();
  }

  // ---- epilogue phase 1: u into acc regs (reads xk as x-tile [p][o])
  float lsum = 0.f;
#pragma unroll
  for (int i = 0; i < 4; i++) {
#pragma unroll
    for (int rg = 0; rg < 4; rg++) {
      int ol = wm0 + i * 16 + qd * 4 + rg;      // local o
      float bv = bias[o0 + ol];
#pragma unroll
      for (int j = 0; j < 4; j++) {
        int pl = wn0 + j * 16 + r;              // local p
        float ev = __expf(acc[i][j][rg] + bv);
        lsum += ev;
        acc[i][j][rg] = (float)xk[pl * 136 + ol] * ev;   // u value
      }
    }
  }
#pragma unroll
  for (int off = 32; off; off >>= 1) lsum += __shfl_down(lsum, off, 64);
  if (ln == 0) rs[wv] = lsum;
  __syncthreads();   // all xk (x-tile) reads done; rs ready
  if (t == 0) atomicAdd(&denom[batch], rs[0] + rs[1] + rs[2] + rs[3]);

  // ---- phase 2: write u-tile into LDS as [o][p] (pad 136)
#pragma unroll
  for (int i = 0; i < 4; i++)
#pragma unroll
    for (int rg = 0; rg < 4; rg++) {
      int ol = wm0 + i * 16 + qd * 4 + rg;
#pragma unroll
      for (int j = 0; j < 4; j++) {
        int pl = wn0 + j * 16 + r;
        xk[ol * 136 + pl] = (_Float16)acc[i][j][rg];
      }
    }
  __syncthreads();

  // ---- phase 3: coalesced half8 stores (256B-contiguous rows)
  _Float16* outb = u + (size_t)batch * SAMP + (size_t)o0 * HWP + p0;
#pragma unroll
  for (int it = 0; it < 8; it++) {
    int ch  = it * 256 + t;     // 2048 chunks: 128 rows x 16
    int row = ch >> 4;
    int ck  = ch & 15;
    half8 v = *(const half8*)(xk + row * 136 + ck * 8);
    *(half8*)(outb + (size_t)row * HWP + ck * 8) = v;
  }
}

// ---- K3: prototypes s[m][c] = (1/1280) * sum_j invd_j * sum_p u ----
__global__ __launch_bounds__(256) void k_proto(const _Float16* __restrict__ u,
                                              const float* __restrict__ denom,
                                              float* __restrict__ sproto) {
  int m = blockIdx.x / 512, c = blockIdx.x % 512;
  int t = threadIdx.x;
  float acc = 0.f;
  for (int j = 0; j < 5; j++) {
    int b = m * 20 + j;
    float invd = 1.0f / denom[b];
    acc += (float)u[(size_t)b * SAMP + (size_t)c * HWP + t] * invd;
  }
#pragma unroll
  for (int off = 32; off; off >>= 1) acc += __shfl_down(acc, off, 64);
  __shared__ float rs[4];
  if ((t & 63) == 0) rs[t >> 6] = acc;
  __syncthreads();
  if (t == 0) sproto[m * 512 + c] = (rs[0] + rs[1] + rs[2] + rs[3]) * (1.0f / 1280.0f);
}

// ---- K4a: per (query n, c-chunk gc of 64): partial dots + qq from u (fp16) ----
__global__ __launch_bounds__(256) void k_part(const _Float16* __restrict__ u,
                                             const float* __restrict__ sproto,
                                             float* __restrict__ part) {
  __shared__ float s_l[5 * 64];
  int n = blockIdx.x >> 3, gc = blockIdx.x & 7;
  int b = (n / 15) * 20 + 5 + (n % 15);
  int t = threadIdx.x;                // position f
  for (int i = t; i < 320; i += 256)
    s_l[i] = sproto[(i >> 6) * 512 + gc * 64 + (i & 63)];
  __syncthreads();
  const _Float16* ub = u + (size_t)b * SAMP + (size_t)gc * 64 * HWP;
  float dot[5] = {0, 0, 0, 0, 0}, qq = 0.f;
#pragma unroll 8
  for (int c = 0; c < 64; c++) {
    float v = (float)ub[c * HWP + t];
    qq += v * v;
#pragma unroll
    for (int m = 0; m < 5; m++) dot[m] += v * s_l[m * 64 + c];
  }
  float* pp = part + (((size_t)n * 8 + gc) * 256 + t) * 6;
  pp[0] = dot[0]; pp[1] = dot[1]; pp[2] = dot[2];
  pp[3] = dot[3]; pp[4] = dot[4]; pp[5] = qq;
}

// ---- K4b: combine partials -> cosine -> softmax(5) -> spatial mean.
// Prototype norms computed in-block from L2-hot sproto (k_sn folded in).
__global__ __launch_bounds__(256) void k_comb(const float* __restrict__ part,
                                             const float* __restrict__ sproto,
                                             float* __restrict__ out) {
  __shared__ float prefs[5];
  int n = blockIdx.x, t = threadIdx.x;
  int wvi = t >> 6, ln = t & 63;
  for (int m = wvi; m < 5; m += 4) {
    float a = 0.f;
    for (int i = ln; i < 512; i += 64) { float v = sproto[m * 512 + i]; a += v * v; }
#pragma unroll
    for (int off = 32; off; off >>= 1) a += __shfl_down(a, off, 64);
    if (ln == 0) prefs[m] = 10.0f / fmaxf(sqrtf(a), 1e-8f);
  }
  __syncthreads();
  float dot[5] = {0, 0, 0, 0, 0}, qq = 0.f;
#pragma unroll
  for (int gc = 0; gc < 8; gc++) {
    const float* pp = part + (((size_t)n * 8 + gc) * 256 + t) * 6;
    dot[0] += pp[0]; dot[1] += pp[1]; dot[2] += pp[2];
    dot[3] += pp[3]; dot[4] += pp[4]; qq += pp[5];
  }
  float iqn = 1.0f / fmaxf(sqrtf(qq), 1e-20f);
  float sc[5], mx = -1e30f;
#pragma unroll
  for (int m = 0; m < 5; m++) { sc[m] = dot[m] * prefs[m] * iqn; mx = fmaxf(mx, sc[m]); }
  float p[5], ssum = 0.f;
#pragma unroll
  for (int m = 0; m < 5; m++) { p[m] = __expf(sc[m] - mx); ssum += p[m]; }
  float rr = 1.0f / ssum;
#pragma unroll
  for (int m = 0; m < 5; m++) {
    float v = p[m] * rr;
#pragma unroll
    for (int off = 32; off; off >>= 1) v += __shfl_down(v, off, 64);
    p[m] = v;
  }
  __shared__ float rsb[4][5];
  if (ln == 0) {
#pragma unroll
    for (int m = 0; m < 5; m++) rsb[wvi][m] = p[m];
  }
  __syncthreads();
  if (t < 5) out[n * 5 + t] =
      (rsb[0][t] + rsb[1][t] + rsb[2][t] + rsb[3][t]) * (1.0f / 256.0f);
}

extern "C" void kernel_launch(void* const* d_in, const int* in_sizes, int n_in,
                              void* d_out, int out_size, void* d_ws, size_t ws_size,
                              hipStream_t stream) {
  const float* x    = (const float*)d_in[0];   // (100,512,16,16)
  const float* W    = (const float*)d_in[1];   // (512,512)
  const float* bias = (const float*)d_in[2];   // (512,)
  float* out = (float*)d_out;                  // (75,5) fp32

  char* ws = (char*)d_ws;
  _Float16* xh     = (_Float16*)(ws + 0);          // 26,214,400 B (dead after gemm)
  float*    part   = (float*)   (ws + 0);          //  2,764,800 B (aliases xh)
  _Float16* Wh     = (_Float16*)(ws + 26214400);   //    524,288 B
  _Float16* u      = (_Float16*)(ws + 26738688);   // 26,214,400 B  u = x*exp(logit)
  float*    denom  = (float*)   (ws + 52953088);   //        512 B
  float*    sproto = (float*)   (ws + 52953600);   //     10,240 B

  hipMemsetAsync(denom, 0, 512, stream);
  k_txpose <<<3456, 256, 0, stream>>>(x, xh, W, Wh);
  k_gemm   <<<800,  256, 0, stream>>>(Wh, xh, bias, u, denom);
  k_proto  <<<2560, 256, 0, stream>>>(u, denom, sproto);
  k_part   <<<600,  256, 0, stream>>>(u, sproto, part);
  k_comb   <<<75,   256, 0, stream>>>(part, sproto, out);
}